// Round 5
// baseline (179.438 us; speedup 1.0000x reference)
//
#include <hip/hip_runtime.h>

// LDPC min-sum layer. B=1024, N=4096, E=16384, colW=4, rowW-1=7.
// Persistent 256-block version: each block processes 4 rows with cross-row
// software pipelining -- while row i runs HBM-heavy phase 3, row i+1's
// e2oLLR is staged into the other half of a double-buffered LDS edge array.
// Phase 3 keeps the lane-transposed coalesced index loads + wave-private
// LDS redistribution (single-buffered scratch, dual wave-level fences).
#define BB   1024
#define NN   4096
#define EE   16384
#define COLW 4
#define ROWW1 7
#define TPB  1024
#define NWAVE (TPB / 64)          // 16
#define GRP_DW (64 * ROWW1)       // 448 dwords per 64-edge group
#define SCR_DW (NWAVE * GRP_DW)   // 7168 dwords (28 KB)
#define NBLK 256
#define RPB  (BB / NBLK)          // 4 rows per block

__global__ __launch_bounds__(TPB) void msl_fused_kernel(
    const float* __restrict__ channelLLR,   // [B,N]
    const float* __restrict__ e2oLLR,       // [B,E]
    const int*   __restrict__ edgeToVar,    // [B,N,4]
    const float* __restrict__ edgeToVarMask,// [B,N,4]
    const int*   __restrict__ oddToEven,    // [B,E]
    const int*   __restrict__ edgeToChk,    // [B,E,7]
    const float* __restrict__ alpha,        // [1]
    float*       __restrict__ out,          // [B,N]
    float*       __restrict__ e2o_out)      // [B,E]
{
    __shared__ __align__(16) float edge_lds[2][EE];   // 128 KB (double-buffered rows)
    __shared__ __align__(16) float scr_lds[SCR_DW];   // 28 KB (llr aliases first NN)
    const int tid  = threadIdx.x;
    const int wave = tid >> 6;
    const int lane = tid & 63;
    const float alph = alpha[0];

    int4   idxreg[NN / TPB];   // current row's edgeToVar (4 x int4)
    float4 mreg[NN / TPB];     // current row's mask

    // ---- prologue: stage row0's e2oLLR into edge_lds[0] ----
    {
        const float4* __restrict__ src = reinterpret_cast<const float4*>(e2oLLR + (size_t)blockIdx.x * EE);
        float4* dst = reinterpret_cast<float4*>(&edge_lds[0][0]);
        #pragma unroll
        for (int k = 0; k < EE / 4 / TPB; ++k) dst[tid + k * TPB] = src[tid + k * TPB];
    }
    __syncthreads();

    // ---- phase 1 (row0): llr -> scr_lds ----
    {
        const int r = blockIdx.x;
        const int4*   __restrict__ ev4 = reinterpret_cast<const int4*>(edgeToVar + (size_t)r * NN * COLW);
        const float4* __restrict__ mk4 = reinterpret_cast<const float4*>(edgeToVarMask + (size_t)r * NN * COLW);
        const float*  __restrict__ chrow = channelLLR + (size_t)r * NN;
        const float* buf = &edge_lds[0][0];
        #pragma unroll
        for (int k = 0; k < NN / TPB; ++k) {
            int n = tid + k * TPB;
            int4  idx = ev4[n];
            float4 m  = mk4[n];
            float acc = chrow[n];
            acc += buf[idx.x] * m.x; acc += buf[idx.y] * m.y;
            acc += buf[idx.z] * m.z; acc += buf[idx.w] * m.w;
            scr_lds[n] = acc;
            idxreg[k] = idx; mreg[k] = m;
        }
    }
    __syncthreads();

    // ---- phase 2 (row0): vllr in place in edge_lds[0] ----
    {
        const int* __restrict__ o2erow = oddToEven + (size_t)blockIdx.x * EE;
        float* buf = &edge_lds[0][0];
        #pragma unroll 8
        for (int k = 0; k < EE / TPB; ++k) {
            int e = tid + k * TPB;
            buf[e] = scr_lds[o2erow[e]] - buf[e];
        }
    }
    __syncthreads();

    for (int i = 0; i < RPB; ++i) {
        const int r = blockIdx.x + NBLK * i;
        float* cur = &edge_lds[i & 1][0];
        float* nxt = &edge_lds[(i + 1) & 1][0];
        const bool has_next = (i < RPB - 1);

        // ---- phase 3 (row r) + interleaved e2oLLR staging of row r+NBLK ----
        float e2oreg[EE / TPB];
        {
            const int* __restrict__ ecrow = edgeToChk + (size_t)r * (size_t)EE * ROWW1;
            float* __restrict__ e2orow = e2o_out + (size_t)r * EE;
            const float4* __restrict__ nsrc = has_next
                ? reinterpret_cast<const float4*>(e2oLLR + (size_t)(r + NBLK) * EE) : nullptr;
            float4* ndst = reinterpret_cast<float4*>(nxt);
            float* __restrict__ scratch = scr_lds + wave * GRP_DW;
            int idx[ROWW1];
            {   // prologue indices for it=0
                const int* __restrict__ p = ecrow + (size_t)wave * GRP_DW + lane;
                #pragma unroll
                for (int j = 0; j < ROWW1; ++j) idx[j] = p[64 * j];
            }
            float4 stage_v;
            #pragma unroll
            for (int it = 0; it < EE / TPB; ++it) {      // 16 iters
                const int g = it * NWAVE + wave;
                // WAR fence: previous iter's readback done before re-scatter
                __builtin_amdgcn_wave_barrier();
                asm volatile("s_waitcnt lgkmcnt(0)" ::: "memory");
                __builtin_amdgcn_wave_barrier();
                // gather vllr + scatter to scratch (stride 64 -> 2-way, free)
                #pragma unroll
                for (int j = 0; j < ROWW1; ++j) scratch[lane + 64 * j] = cur[idx[j]];
                // staging interleave: 1 float4 load / 1 ds_write per thread per 4 iters
                if (has_next) {
                    if ((it & 3) == 0)      stage_v = nsrc[tid + (it >> 2) * TPB];
                    else if ((it & 3) == 2) ndst[tid + (it >> 2) * TPB] = stage_v;
                }
                // prefetch next group's indices (vmcnt stays in flight over fences)
                if (it + 1 < EE / TPB) {
                    const int* __restrict__ p = ecrow + (size_t)(g + NWAVE) * GRP_DW + lane;
                    #pragma unroll
                    for (int j = 0; j < ROWW1; ++j) idx[j] = p[64 * j];
                }
                // RAW fence: scatter committed before readback
                __builtin_amdgcn_wave_barrier();
                asm volatile("s_waitcnt lgkmcnt(0)" ::: "memory");
                __builtin_amdgcn_wave_barrier();
                // readback edge-major (stride 7 coprime 32 -> free), reduce
                float mn = 3.0e38f;
                unsigned sgn = 0u;
                const float* __restrict__ sb = scratch + lane * ROWW1;
                #pragma unroll
                for (int j = 0; j < ROWW1; ++j) {
                    float u = sb[j];
                    sgn ^= __float_as_uint(u);
                    mn = fminf(mn, fabsf(u));
                }
                float val = mn * alph;
                float rr = __uint_as_float(__float_as_uint(val) ^ (sgn & 0x80000000u));
                e2oreg[it] = rr;                          // edge 64g+lane
                e2orow[64 * g + lane] = rr;               // coalesced store
            }
        }
        __syncthreads();

        // ---- stash e2o into cur (overwrite vllr; all gathers done) ----
        #pragma unroll
        for (int k = 0; k < EE / TPB; ++k) cur[tid + k * TPB] = e2oreg[k];
        __syncthreads();

        // ---- phase 4 (row r) merged with phase 1 (row r+NBLK) ----
        {
            const float* __restrict__ chrow = channelLLR + (size_t)r * NN;
            float* __restrict__ outrow = out + (size_t)r * NN;
            #pragma unroll
            for (int k = 0; k < NN / TPB; ++k) {
                int n = tid + k * TPB;
                int4  idx = idxreg[k];
                float4 m  = mreg[k];
                float acc = chrow[n];
                acc += cur[idx.x] * m.x; acc += cur[idx.y] * m.y;
                acc += cur[idx.z] * m.z; acc += cur[idx.w] * m.w;
                outrow[n] = acc;
            }
        }
        if (has_next) {
            const int rn = r + NBLK;
            const int4*   __restrict__ ev4 = reinterpret_cast<const int4*>(edgeToVar + (size_t)rn * NN * COLW);
            const float4* __restrict__ mk4 = reinterpret_cast<const float4*>(edgeToVarMask + (size_t)rn * NN * COLW);
            const float*  __restrict__ chrow = channelLLR + (size_t)rn * NN;
            #pragma unroll
            for (int k = 0; k < NN / TPB; ++k) {
                int n = tid + k * TPB;
                int4  idx = ev4[n];
                float4 m  = mk4[n];
                float acc = chrow[n];
                acc += nxt[idx.x] * m.x; acc += nxt[idx.y] * m.y;
                acc += nxt[idx.z] * m.z; acc += nxt[idx.w] * m.w;
                scr_lds[n] = acc;                         // llr(rn)
                idxreg[k] = idx; mreg[k] = m;
            }
            __syncthreads();                              // llr complete before phase 2
            // ---- phase 2 (row rn): vllr in place in nxt ----
            const int* __restrict__ o2erow = oddToEven + (size_t)rn * EE;
            #pragma unroll 8
            for (int k = 0; k < EE / TPB; ++k) {
                int e = tid + k * TPB;
                nxt[e] = scr_lds[o2erow[e]] - nxt[e];
            }
        }
        __syncthreads();
    }
}

extern "C" void kernel_launch(void* const* d_in, const int* in_sizes, int n_in,
                              void* d_out, int out_size, void* d_ws, size_t ws_size,
                              hipStream_t stream) {
    const float* channelLLR    = (const float*)d_in[0];
    const float* e2oLLR        = (const float*)d_in[1];
    // d_in[2] = maxColWeight (int scalar, ==4, baked in)
    const int*   edgeToVar     = (const int*)d_in[3];
    const float* edgeToVarMask = (const float*)d_in[4];
    const int*   oddToEven     = (const int*)d_in[5];
    const int*   edgeToChk     = (const int*)d_in[6];
    // d_in[7] = rowWeight (int scalar, ==8, baked in)
    const float* alpha         = (const float*)d_in[8];

    float* out     = (float*)d_out;                    // [B,N]
    float* e2o_out = (float*)d_out + (size_t)BB * NN;  // [B,E]

    msl_fused_kernel<<<NBLK, TPB, 0, stream>>>(
        channelLLR, e2oLLR, edgeToVar, edgeToVarMask,
        oddToEven, edgeToChk, alpha, out, e2o_out);
}